// Round 13
// baseline (134.462 us; speedup 1.0000x reference)
//
#include <hip/hip_runtime.h>
#include <hip/hip_cooperative_groups.h>

namespace cg = cooperative_groups;

#define LSEQ 8192
#define CH   256

typedef __attribute__((ext_vector_type(8)))  short short8;
typedef __attribute__((ext_vector_type(4)))  short short4v;
typedef __attribute__((ext_vector_type(16))) float f32x16;
typedef unsigned int u32;

// bf16 converts via v_cvt_pk_bf16_f32 (RNE)
__device__ __forceinline__ short f2bf(float f) {
  u32 r;
  asm("v_cvt_pk_bf16_f32 %0, %1, %1" : "=v"(r) : "v"(f));
  return (short)r;
}
__device__ __forceinline__ u32 pk2bf(float a, float b) {
  u32 r;
  asm("v_cvt_pk_bf16_f32 %0, %1, %2" : "=v"(r) : "v"(a), "v"(b));
  return r;
}
__device__ __forceinline__ short8 cvt8(float4 a, float4 b) {
  union { u32 u[4]; short8 s; } v;
  v.u[0] = pk2bf(a.x, a.y); v.u[1] = pk2bf(a.z, a.w);
  v.u[2] = pk2bf(b.x, b.y); v.u[3] = pk2bf(b.z, b.w);
  return v.s;
}
__device__ __forceinline__ short4v pk4bf(float a, float b, float c, float d) {
  union { u32 u[2]; short4v s; } v;
  v.u[0] = pk2bf(a, b); v.u[1] = pk2bf(c, d);
  return v.s;
}
__device__ inline f32x16 mfma32(short8 a, short8 b, f32x16 c) {
  return __builtin_amdgcn_mfma_f32_32x32x16_bf16(a, b, c, 0, 0, 0);
}
// async global -> LDS, 16B per lane; dest = wave-uniform base (+ lane*16 by HW)
__device__ __forceinline__ void gload16(const void* g, void* l) {
  __builtin_amdgcn_global_load_lds(
      (const __attribute__((address_space(1))) u32*)g,
      (__attribute__((address_space(3))) u32*)l, 16, 0, 0);
}

// ===========================================================================
// FUSED cooperative kernel: 256 blocks x 256 threads, 64KB static LDS.
//  P0: xb = bf16(x)                       (grid-stride, 4 iters)
//  P1: qkv — 384 tiles, each block does t = b, b+256  (R11-verified GEMM)
//  P2: gram MT = V^T K (b<64) + scalar reductions (b==64)
//  P3: final (b<128)
// ===========================================================================
__global__ __launch_bounds__(256, 2) void fused_kernel(
    const float* __restrict__ x,
    const float* __restrict__ Wq, const float* __restrict__ bq,
    const float* __restrict__ Wk, const float* __restrict__ bk,
    const float* __restrict__ Wv, const float* __restrict__ bv,
    short* __restrict__ xb, short* __restrict__ Qb,
    short* __restrict__ KTb, short* __restrict__ VTb,
    float* __restrict__ sp, float* __restrict__ MT,
    float* __restrict__ scal, float* __restrict__ out)
{
  cg::grid_group grid = cg::this_grid();
  __shared__ __align__(16) char smem[65536];   // 64KB, phase-aliased

  const int b = blockIdx.x, tid = threadIdx.x;
  const int wid = tid >> 6, lane = tid & 63, l31 = lane & 31, hi = lane >> 5;

  // ================= P0: x -> bf16 xb ====================================
  for (int i = b * 256 + tid; i < LSEQ * CH / 8; i += 256 * 256) {
    const float4* s4 = (const float4*)(x + (size_t)i * 8);
    *(short8*)(xb + (size_t)i * 8) = cvt8(s4[0], s4[1]);
  }
  grid.sync();

  // ================= P1: QKV projection (384 tiles over 256 blocks) =======
  {
    short* wt = (short*)smem;                          // [128][256] = 64KB
    float (*colred)[128] = (float(*)[128])smem;        // aliases wt (guarded)

    for (int t = b; t < 384; t += 256) {
      const int m = t >> 7, tt = t & 127;
      const float* W  = (m == 0) ? Wq : ((m == 1) ? Wk : Wv);
      const float* bp = (m == 0) ? bq : ((m == 1) ? bk : bv);
      const int rb = tt >> 1, cb = tt & 1;
      const int row0 = rb * 128, col0 = cb * 128;

      __syncthreads();               // prior tile's LDS consumers done

      // m=0 tiles zero MT (disjoint slices; read only in P2/P3)
      if (m == 0 && tid < 128) {
        float4 z = {0.f, 0.f, 0.f, 0.f};
        ((float4*)(MT + (size_t)tt * 512))[tid] = z;
      }

#pragma unroll
      for (int i = 0; i < 16; ++i) {
        int g = i * 256 + tid;       // 16B bf16 chunk (8 elems / 32B fp32)
        int rr = g >> 5, p = g & 31;
        const float4* src = (const float4*)(W + (col0 + rr) * CH + ((p ^ (rr & 31)) * 8));
        *(short8*)(&wt[rr * 256 + p * 8]) = cvt8(src[0], src[1]);
      }
      __syncthreads();

      const int wrow0 = row0 + wid * 32;
      short8 af[16];
#pragma unroll
      for (int kd = 0; kd < 16; ++kd)
        af[kd] = *(const short8*)(xb + (size_t)(wrow0 + l31) * CH + kd * 16 + hi * 8);

      f32x16 acc[4] = {};
#pragma unroll
      for (int kd = 0; kd < 16; ++kd)
#pragma unroll
        for (int nf = 0; nf < 4; ++nf) {
          int r = nf * 32 + l31;
          short8 bf = *(const short8*)(&wt[r * 256 + (((kd * 2 + hi) ^ (r & 31)) * 8)]);
          acc[nf] = mfma32(af[kd], bf, acc[nf]);   // D: row=x-row, col=outcol
        }
      __syncthreads();               // all wt reads done before colred alias

      // D layout: col = l31 (+32*nf), row = wrow0 + (r&3) + 8*(r>>2) + 4*hi
#pragma unroll
      for (int nf = 0; nf < 4; ++nf) {
        int col = col0 + nf * 32 + l31;
        float bias = bp[col];
        float cs = 0.f;
        if (m == 0) {
#pragma unroll
          for (int r = 0; r < 16; ++r) {
            float y = acc[nf][r] + bias;
            cs += y;
            int row = wrow0 + (r & 3) + 8 * (r >> 2) + 4 * hi;
            Qb[(size_t)row * CH + col] = f2bf(y);
          }
        } else {
          short* dst = (m == 1) ? KTb : VTb;
#pragma unroll
          for (int g = 0; g < 4; ++g) {
            float y0 = acc[nf][g * 4 + 0] + bias;
            float y1 = acc[nf][g * 4 + 1] + bias;
            float y2 = acc[nf][g * 4 + 2] + bias;
            float y3 = acc[nf][g * 4 + 3] + bias;
            cs += (y0 + y1) + (y2 + y3);
            *(short4v*)(&dst[(size_t)col * LSEQ + wrow0 + g * 8 + hi * 4]) =
                pk4bf(y0, y1, y2, y3);
          }
        }
        cs += __shfl_xor(cs, 32);    // add other hi-half: 32-row sum
        if (hi == 0) colred[wid][nf * 32 + l31] = cs;
      }
      __syncthreads();
      if (tid < 128) {
        float s = colred[0][tid] + colred[1][tid] + colred[2][tid] + colred[3][tid];
        sp[((size_t)m * 64 + rb) * 256 + col0 + tid] = s;   // plain partials
      }
    }
  }
  grid.sync();

  // ================= P2: gram (b<64) + scalars (b==64) ====================
  if (b == 64) {
    float s0 = 0.f, s1 = 0.f, s2 = 0.f;
    for (int rb = 0; rb < 64; ++rb) {
      s0 += sp[(size_t)(0 * 64 + rb) * 256 + tid];
      s1 += sp[(size_t)(1 * 64 + rb) * 256 + tid];
      s2 += sp[(size_t)(2 * 64 + rb) * 256 + tid];
    }
    scal[1 + tid] = s2;              // colsum
    float* red = (float*)smem;
    red[tid] = s0 * s1;              // sq[c]*sk[c]
    __syncthreads();
#pragma unroll
    for (int st = 128; st > 0; st >>= 1) {
      if (tid < st) red[tid] += red[tid + st];
      __syncthreads();
    }
    if (tid == 0) scal[0] = red[0];
  } else if (b < 64) {
    short* at = (short*)smem;                  // [128][128] VT tile
    short* bt = (short*)(smem + 32768);        // [128][128] KT tile

    const int tile = b & 3, split = b >> 2;    // split 0..15
    const int d0 = (tile >> 1) * 128, c0 = (tile & 1) * 128;
    const int wr = wid >> 1, wc = wid & 1;

    f32x16 acc[2][2] = {};

#pragma unroll
    for (int jj = 0; jj < 4; ++jj) {
      const int j0 = split * 512 + jj * 128;
      __syncthreads();               // prior-stage readers done
#pragma unroll
      for (int i = 0; i < 8; ++i) {
        int g = i * 256 + tid, rr = g >> 4, p = g & 15;
        gload16(VTb + (size_t)(d0 + rr) * LSEQ + j0 + ((p ^ (rr & 15)) * 8),
                &at[(i * 256 + wid * 64) * 8]);
      }
#pragma unroll
      for (int i = 0; i < 8; ++i) {
        int g = i * 256 + tid, rr = g >> 4, p = g & 15;
        gload16(KTb + (size_t)(c0 + rr) * LSEQ + j0 + ((p ^ (rr & 15)) * 8),
                &bt[(i * 256 + wid * 64) * 8]);
      }
      __syncthreads();               // drains vmcnt + barrier

#pragma unroll
      for (int kd = 0; kd < 8; ++kd) {
        int ra0 = wr * 64 + l31, ra1 = ra0 + 32;
        int rb0 = wc * 64 + l31, rb1 = rb0 + 32;
        int ck = kd * 2 + hi;
        short8 a0 = *(const short8*)(&at[ra0 * 128 + ((ck ^ (ra0 & 15)) * 8)]);
        short8 a1 = *(const short8*)(&at[ra1 * 128 + ((ck ^ (ra1 & 15)) * 8)]);
        short8 b0 = *(const short8*)(&bt[rb0 * 128 + ((ck ^ (rb0 & 15)) * 8)]);
        short8 b1 = *(const short8*)(&bt[rb1 * 128 + ((ck ^ (rb1 & 15)) * 8)]);
        acc[0][0] = mfma32(a0, b0, acc[0][0]);
        acc[0][1] = mfma32(a0, b1, acc[0][1]);
        acc[1][0] = mfma32(a1, b0, acc[1][0]);
        acc[1][1] = mfma32(a1, b1, acc[1][1]);
      }
    }

#pragma unroll
    for (int mt = 0; mt < 2; ++mt)
#pragma unroll
      for (int nt = 0; nt < 2; ++nt) {
        int ccol = c0 + wc * 64 + nt * 32 + l31;
#pragma unroll
        for (int r = 0; r < 16; ++r) {
          int r2 = r ^ (split & 15); // split-dependent issue order
          int drow = d0 + wr * 64 + mt * 32 + (r2 & 3) + 8 * (r2 >> 2) + 4 * hi;
          atomicAdd(&MT[drow * CH + ccol], acc[mt][nt][r2]);
        }
      }
  }
  grid.sync();

  // ================= P3: final (b<128) ====================================
  if (b < 128) {
    short* wt = (short*)smem;                  // [128][256] bf16 MT slice

    const float Zinv = 1.0f / (67108864.0f + scal[0] * (1.0f / 8192.0f));
    const int rb = b >> 1, cb = b & 1;
    const int row0 = rb * 128, col0 = cb * 128;

#pragma unroll
    for (int i = 0; i < 16; ++i) {
      int g = i * 256 + tid;
      int rr = g >> 5, p = g & 31;
      const float4* src = (const float4*)(MT + (col0 + rr) * CH + ((p ^ (rr & 31)) * 8));
      *(short8*)(&wt[rr * 256 + p * 8]) = cvt8(src[0], src[1]);
    }
    __syncthreads();

    const int wrow0 = row0 + wid * 32;
    short8 qf[16];
#pragma unroll
    for (int kd = 0; kd < 16; ++kd)
      qf[kd] = *(const short8*)(Qb + (size_t)(wrow0 + l31) * CH + kd * 16 + hi * 8);

    f32x16 acc[4] = {};
#pragma unroll
    for (int kd = 0; kd < 16; ++kd)
#pragma unroll
      for (int nf = 0; nf < 4; ++nf) {
        int r = nf * 32 + l31;
        short8 bf = *(const short8*)(&wt[r * 256 + (((kd * 2 + hi) ^ (r & 31)) * 8)]);
        acc[nf] = mfma32(qf[kd], bf, acc[nf]);
      }

#pragma unroll
    for (int nf = 0; nf < 4; ++nf) {
      int col = col0 + nf * 32 + l31;
      float cs = scal[1 + col];
#pragma unroll
      for (int r = 0; r < 16; ++r) {
        int row = wrow0 + (r & 3) + 8 * (r >> 2) + 4 * hi;
        out[(size_t)row * CH + col] = (cs + acc[nf][r] * (1.0f / 8192.0f)) * Zinv;
      }
    }
  }
}

// ===========================================================================
// FALLBACK path: verified R11 three-kernel pipeline (39.15us), byte-identical.
// ===========================================================================
__global__ __launch_bounds__(256) void qkv_kernel(
    const float* __restrict__ x,
    const float* __restrict__ Wq, const float* __restrict__ bq,
    const float* __restrict__ Wk, const float* __restrict__ bk,
    const float* __restrict__ Wv, const float* __restrict__ bv,
    short* __restrict__ Qb, short* __restrict__ KTb, short* __restrict__ VTb,
    float* __restrict__ sp, float* __restrict__ MT)
{
  const int m = blockIdx.y;
  const float* W  = (m == 0) ? Wq : ((m == 1) ? Wk : Wv);
  const float* bp = (m == 0) ? bq : ((m == 1) ? bk : bv);
  const int rb = blockIdx.x >> 1, cb = blockIdx.x & 1;
  const int row0 = rb * 128, col0 = cb * 128;

  __shared__ __align__(16) short wt[128 * 256];
  __shared__ float colred[4][128];

  const int tid = threadIdx.x;

  if (m == 0 && tid < 128) {
    float4 z = {0.f, 0.f, 0.f, 0.f};
    ((float4*)(MT + (size_t)blockIdx.x * 512))[tid] = z;
  }

#pragma unroll
  for (int i = 0; i < 16; ++i) {
    int g = i * 256 + tid;
    int rr = g >> 5, p = g & 31;
    const float4* src = (const float4*)(W + (col0 + rr) * CH + ((p ^ (rr & 31)) * 8));
    *(short8*)(&wt[rr * 256 + p * 8]) = cvt8(src[0], src[1]);
  }
  __syncthreads();

  const int wid = tid >> 6, lane = tid & 63, l31 = lane & 31, hi = lane >> 5;
  const int wrow0 = row0 + wid * 32;

  f32x16 acc[4] = {};
#pragma unroll
  for (int kd = 0; kd < 16; ++kd) {
    const float4* xs = (const float4*)(x + (size_t)(wrow0 + l31) * CH + kd * 16 + hi * 8);
    short8 af = cvt8(xs[0], xs[1]);
#pragma unroll
    for (int nf = 0; nf < 4; ++nf) {
      int r = nf * 32 + l31;
      short8 bf = *(const short8*)(&wt[r * 256 + (((kd * 2 + hi) ^ (r & 31)) * 8)]);
      acc[nf] = mfma32(af, bf, acc[nf]);
    }
  }

#pragma unroll
  for (int nf = 0; nf < 4; ++nf) {
    int col = col0 + nf * 32 + l31;
    float bias = bp[col];
    float cs = 0.f;
    if (m == 0) {
#pragma unroll
      for (int r = 0; r < 16; ++r) {
        float y = acc[nf][r] + bias;
        cs += y;
        int row = wrow0 + (r & 3) + 8 * (r >> 2) + 4 * hi;
        Qb[(size_t)row * CH + col] = f2bf(y);
      }
    } else {
      short* dst = (m == 1) ? KTb : VTb;
#pragma unroll
      for (int g = 0; g < 4; ++g) {
        float y0 = acc[nf][g * 4 + 0] + bias;
        float y1 = acc[nf][g * 4 + 1] + bias;
        float y2 = acc[nf][g * 4 + 2] + bias;
        float y3 = acc[nf][g * 4 + 3] + bias;
        cs += (y0 + y1) + (y2 + y3);
        *(short4v*)(&dst[(size_t)col * LSEQ + wrow0 + g * 8 + hi * 4]) =
            pk4bf(y0, y1, y2, y3);
      }
    }
    cs += __shfl_xor(cs, 32);
    if (hi == 0) colred[wid][nf * 32 + l31] = cs;
  }
  __syncthreads();
  if (tid < 128) {
    float s = colred[0][tid] + colred[1][tid] + colred[2][tid] + colred[3][tid];
    sp[((size_t)m * 64 + rb) * 256 + col0 + tid] = s;
  }
}

__global__ __launch_bounds__(256) void gram_kernel(
    const short* __restrict__ VTb, const short* __restrict__ KTb,
    const float* __restrict__ sp, float* __restrict__ MT,
    float* __restrict__ scal)
{
  __shared__ __align__(16) short at[128 * 128];
  __shared__ __align__(16) short bt[128 * 128];

  const int tid = threadIdx.x;

  if (blockIdx.x == 64) {
    float s0 = 0.f, s1 = 0.f, s2 = 0.f;
    for (int rb = 0; rb < 64; ++rb) {
      s0 += sp[(size_t)(0 * 64 + rb) * 256 + tid];
      s1 += sp[(size_t)(1 * 64 + rb) * 256 + tid];
      s2 += sp[(size_t)(2 * 64 + rb) * 256 + tid];
    }
    scal[1 + tid] = s2;
    float* red = (float*)at;
    red[tid] = s0 * s1;
    __syncthreads();
#pragma unroll
    for (int st = 128; st > 0; st >>= 1) {
      if (tid < st) red[tid] += red[tid + st];
      __syncthreads();
    }
    if (tid == 0) scal[0] = red[0];
    return;
  }

  const int tile = blockIdx.x & 3, split = blockIdx.x >> 2;
  const int d0 = (tile >> 1) * 128, c0 = (tile & 1) * 128;
  const int wid = tid >> 6, lane = tid & 63;
  const int l31 = lane & 31, hi = lane >> 5;
  const int wr = wid >> 1, wc = wid & 1;

  f32x16 acc[2][2] = {};

#pragma unroll
  for (int jj = 0; jj < 4; ++jj) {
    const int j0 = split * 512 + jj * 128;
    __syncthreads();
#pragma unroll
    for (int i = 0; i < 8; ++i) {
      int g = i * 256 + tid, rr = g >> 4, p = g & 15;
      gload16(VTb + (size_t)(d0 + rr) * LSEQ + j0 + ((p ^ (rr & 15)) * 8),
              &at[(i * 256 + wid * 64) * 8]);
    }
#pragma unroll
    for (int i = 0; i < 8; ++i) {
      int g = i * 256 + tid, rr = g >> 4, p = g & 15;
      gload16(KTb + (size_t)(c0 + rr) * LSEQ + j0 + ((p ^ (rr & 15)) * 8),
              &bt[(i * 256 + wid * 64) * 8]);
    }
    __syncthreads();

#pragma unroll
    for (int kd = 0; kd < 8; ++kd) {
      int ra0 = wr * 64 + l31, ra1 = ra0 + 32;
      int rb0 = wc * 64 + l31, rb1 = rb0 + 32;
      int ck = kd * 2 + hi;
      short8 a0 = *(const short8*)(&at[ra0 * 128 + ((ck ^ (ra0 & 15)) * 8)]);
      short8 a1 = *(const short8*)(&at[ra1 * 128 + ((ck ^ (ra1 & 15)) * 8)]);
      short8 b0 = *(const short8*)(&bt[rb0 * 128 + ((ck ^ (rb0 & 15)) * 8)]);
      short8 b1 = *(const short8*)(&bt[rb1 * 128 + ((ck ^ (rb1 & 15)) * 8)]);
      acc[0][0] = mfma32(a0, b0, acc[0][0]);
      acc[0][1] = mfma32(a0, b1, acc[0][1]);
      acc[1][0] = mfma32(a1, b0, acc[1][0]);
      acc[1][1] = mfma32(a1, b1, acc[1][1]);
    }
  }

#pragma unroll
  for (int mt = 0; mt < 2; ++mt)
#pragma unroll
    for (int nt = 0; nt < 2; ++nt) {
      int ccol = c0 + wc * 64 + nt * 32 + l31;
#pragma unroll
      for (int r = 0; r < 16; ++r) {
        int r2 = r ^ (split & 15);
        int drow = d0 + wr * 64 + mt * 32 + (r2 & 3) + 8 * (r2 >> 2) + 4 * hi;
        atomicAdd(&MT[drow * CH + ccol], acc[mt][nt][r2]);
      }
    }
}

__global__ __launch_bounds__(256) void final_kernel(
    const short* __restrict__ Qb, const float* __restrict__ MT,
    const float* __restrict__ scal, float* __restrict__ out)
{
  __shared__ __align__(16) short wt[128 * 256];

  const int tid = threadIdx.x;
  const float Zinv = 1.0f / (67108864.0f + scal[0] * (1.0f / 8192.0f));

  const int rb = blockIdx.x >> 1, cb = blockIdx.x & 1;
  const int row0 = rb * 128, col0 = cb * 128;

#pragma unroll
  for (int i = 0; i < 16; ++i) {
    int g = i * 256 + tid;
    int rr = g >> 5, p = g & 31;
    const float4* src = (const float4*)(MT + (col0 + rr) * CH + ((p ^ (rr & 31)) * 8));
    *(short8*)(&wt[rr * 256 + p * 8]) = cvt8(src[0], src[1]);
  }
  __syncthreads();

  const int wid = tid >> 6, lane = tid & 63, l31 = lane & 31, hi = lane >> 5;
  const int wrow0 = row0 + wid * 32;

  short8 qf[16];
#pragma unroll
  for (int kd = 0; kd < 16; ++kd)
    qf[kd] = *(const short8*)(Qb + (size_t)(wrow0 + l31) * CH + kd * 16 + hi * 8);

  f32x16 acc[4] = {};
#pragma unroll
  for (int kd = 0; kd < 16; ++kd)
#pragma unroll
    for (int nf = 0; nf < 4; ++nf) {
      int r = nf * 32 + l31;
      short8 bf = *(const short8*)(&wt[r * 256 + (((kd * 2 + hi) ^ (r & 31)) * 8)]);
      acc[nf] = mfma32(qf[kd], bf, acc[nf]);
    }

#pragma unroll
  for (int nf = 0; nf < 4; ++nf) {
    int col = col0 + nf * 32 + l31;
    float cs = scal[1 + col];
#pragma unroll
    for (int r = 0; r < 16; ++r) {
      int row = wrow0 + (r & 3) + 8 * (r >> 2) + 4 * hi;
      out[(size_t)row * CH + col] = (cs + acc[nf][r] * (1.0f / 8192.0f)) * Zinv;
    }
  }
}

// ---------------------------------------------------------------------------
extern "C" void kernel_launch(void* const* d_in, const int* in_sizes, int n_in,
                              void* d_out, int out_size, void* d_ws, size_t ws_size,
                              hipStream_t stream) {
  const float* x  = (const float*)d_in[0];
  const float* Wq = (const float*)d_in[1];
  const float* bq = (const float*)d_in[2];
  const float* Wk = (const float*)d_in[3];
  const float* bk = (const float*)d_in[4];
  const float* Wv = (const float*)d_in[5];
  const float* bv = (const float*)d_in[6];
  float* out = (float*)d_out;

  // ws: xb(4MB) | Q(4MB) | KT(4MB) | VT(4MB) | MT(256KB) | sp(192KB) | scal
  char* ws = (char*)d_ws;
  short* xb  = (short*)ws;
  short* Qb  = xb  + (size_t)LSEQ * CH;
  short* KTb = Qb  + (size_t)LSEQ * CH;
  short* VTb = KTb + (size_t)CH * LSEQ;
  float* MT   = (float*)(VTb + (size_t)CH * LSEQ);
  float* sp   = MT + (size_t)CH * CH;          // [3][64][256] partial col-sums
  float* scal = sp + (size_t)3 * 64 * 256;     // [0]=zs, [1..256]=colsum

  void* args[] = {&x, &Wq, &bq, &Wk, &bk, &Wv, &bv,
                  &xb, &Qb, &KTb, &VTb, &sp, &MT, &scal, &out};
  hipError_t err = hipLaunchCooperativeKernel((void*)fused_kernel, dim3(256),
                                              dim3(256), args, 0, stream);
  if (err != hipSuccess) {
    // verified R11 fallback (identical outputs)
    qkv_kernel<<<dim3(128, 3), 256, 0, stream>>>(x, Wq, bq, Wk, bk, Wv, bv,
                                                 Qb, KTb, VTb, sp, MT);
    gram_kernel<<<65, 256, 0, stream>>>(VTb, KTb, sp, MT, scal);
    final_kernel<<<128, 256, 0, stream>>>(Qb, MT, scal, out);
  }
}

// Round 14
// 50.367 us; speedup vs baseline: 2.6697x; 2.6697x over previous
//
#include <hip/hip_runtime.h>

#define LSEQ 8192
#define CH   256

typedef __attribute__((ext_vector_type(8)))  short short8;
typedef __attribute__((ext_vector_type(4)))  short short4v;
typedef __attribute__((ext_vector_type(16))) float f32x16;
typedef unsigned int u32;

// bf16 converts via v_cvt_pk_bf16_f32 (RNE)
__device__ __forceinline__ short f2bf(float f) {
  u32 r;
  asm("v_cvt_pk_bf16_f32 %0, %1, %1" : "=v"(r) : "v"(f));
  return (short)r;
}
__device__ __forceinline__ u32 pk2bf(float a, float b) {
  u32 r;
  asm("v_cvt_pk_bf16_f32 %0, %1, %2" : "=v"(r) : "v"(a), "v"(b));
  return r;
}
__device__ __forceinline__ short8 cvt8(float4 a, float4 b) {
  union { u32 u[4]; short8 s; } v;
  v.u[0] = pk2bf(a.x, a.y); v.u[1] = pk2bf(a.z, a.w);
  v.u[2] = pk2bf(b.x, b.y); v.u[3] = pk2bf(b.z, b.w);
  return v.s;
}
__device__ __forceinline__ short4v pk4bf(float a, float b, float c, float d) {
  union { u32 u[2]; short4v s; } v;
  v.u[0] = pk2bf(a, b); v.u[1] = pk2bf(c, d);
  return v.s;
}
__device__ inline f32x16 mfma32(short8 a, short8 b, f32x16 c) {
  return __builtin_amdgcn_mfma_f32_32x32x16_bf16(a, b, c, 0, 0, 0);
}
// async global -> LDS, 16B per lane; dest = wave-uniform base (+ lane*16 by HW)
__device__ __forceinline__ void gload16(const void* g, void* l) {
  __builtin_amdgcn_global_load_lds(
      (const __attribute__((address_space(1))) u32*)g,
      (__attribute__((address_space(3))) u32*)l, 16, 0, 0);
}

// ---------------------------------------------------------------------------
// Kernel 1: QKV projection. Grid (64, 3): block = (rb, m), covers 128 rows x
// 256 outcols by looping cb = 0,1 with x-fragments loaded ONCE to registers.
//   m=0 -> Qb [row][c] bf16 row-major   (+ zero MT: 64 blocks x 1024 floats)
//   m=1 -> KTb[c][row] bf16 transposed
//   m=2 -> VTb[d][row] bf16 transposed
// Column-sum partials sp[m][rb][col] plain-stored (no atomics, no memset).
// Inner GEMM/layout byte-identical to R11-verified kernel.
// ---------------------------------------------------------------------------
__global__ __launch_bounds__(256) void qkv_kernel(
    const float* __restrict__ x,
    const float* __restrict__ Wq, const float* __restrict__ bq,
    const float* __restrict__ Wk, const float* __restrict__ bk,
    const float* __restrict__ Wv, const float* __restrict__ bv,
    short* __restrict__ Qb, short* __restrict__ KTb, short* __restrict__ VTb,
    float* __restrict__ sp, float* __restrict__ MT)
{
  const int m = blockIdx.y;
  const float* W  = (m == 0) ? Wq : ((m == 1) ? Wk : Wv);
  const float* bp = (m == 0) ? bq : ((m == 1) ? bk : bv);
  const int rb = blockIdx.x;
  const int row0 = rb * 128;

  __shared__ __align__(16) short wt[128 * 256];   // 64KB
  __shared__ float colred[4][128];

  const int tid = threadIdx.x;

  // m=0 blocks zero MT (64 blocks x 1024 floats, disjoint; read only by gram)
  if (m == 0) {
    float4 z = {0.f, 0.f, 0.f, 0.f};
    ((float4*)(MT + (size_t)rb * 1024))[tid] = z;
  }

  const int wid = tid >> 6, lane = tid & 63, l31 = lane & 31, hi = lane >> 5;
  const int wrow0 = row0 + wid * 32;

  // x fragments: loaded once, reused for both col-blocks
  short8 af[16];
#pragma unroll
  for (int kd = 0; kd < 16; ++kd) {
    const float4* xs = (const float4*)(x + (size_t)(wrow0 + l31) * CH + kd * 16 + hi * 8);
    af[kd] = cvt8(xs[0], xs[1]);
  }

  for (int cb = 0; cb < 2; ++cb) {
    const int col0 = cb * 128;
    __syncthreads();                   // prior wt/colred consumers done

#pragma unroll
    for (int i = 0; i < 16; ++i) {
      int g = i * 256 + tid;           // 16B bf16 chunk (8 elems / 32B fp32)
      int rr = g >> 5, p = g & 31;
      const float4* src = (const float4*)(W + (col0 + rr) * CH + ((p ^ (rr & 31)) * 8));
      *(short8*)(&wt[rr * 256 + p * 8]) = cvt8(src[0], src[1]);
    }
    __syncthreads();

    f32x16 acc[4] = {};
#pragma unroll
    for (int kd = 0; kd < 16; ++kd)
#pragma unroll
      for (int nf = 0; nf < 4; ++nf) {
        int r = nf * 32 + l31;
        short8 bf = *(const short8*)(&wt[r * 256 + (((kd * 2 + hi) ^ (r & 31)) * 8)]);
        acc[nf] = mfma32(af[kd], bf, acc[nf]);   // D: row=x-row, col=outcol
      }

    // D layout: col = l31 (+32*nf), row = wrow0 + (r&3) + 8*(r>>2) + 4*hi
#pragma unroll
    for (int nf = 0; nf < 4; ++nf) {
      int col = col0 + nf * 32 + l31;
      float bias = bp[col];
      float cs = 0.f;
      if (m == 0) {
#pragma unroll
        for (int r = 0; r < 16; ++r) {
          float y = acc[nf][r] + bias;
          cs += y;
          int row = wrow0 + (r & 3) + 8 * (r >> 2) + 4 * hi;
          Qb[(size_t)row * CH + col] = f2bf(y);
        }
      } else {
        short* dst = (m == 1) ? KTb : VTb;
#pragma unroll
        for (int g = 0; g < 4; ++g) {
          float y0 = acc[nf][g * 4 + 0] + bias;
          float y1 = acc[nf][g * 4 + 1] + bias;
          float y2 = acc[nf][g * 4 + 2] + bias;
          float y3 = acc[nf][g * 4 + 3] + bias;
          cs += (y0 + y1) + (y2 + y3);
          *(short4v*)(&dst[(size_t)col * LSEQ + wrow0 + g * 8 + hi * 4]) =
              pk4bf(y0, y1, y2, y3);
        }
      }
      cs += __shfl_xor(cs, 32);        // add other hi-half: 32-row sum
      if (hi == 0) colred[wid][nf * 32 + l31] = cs;
    }
    __syncthreads();
    if (tid < 128) {
      float s = colred[0][tid] + colred[1][tid] + colred[2][tid] + colred[3][tid];
      sp[((size_t)m * 64 + rb) * 256 + col0 + tid] = s;   // plain partials
    }
  }
}

// ---------------------------------------------------------------------------
// Kernel 2: blocks 0..127: MT[d][c] += V^T K partials (fp32 atomics),
//   4 output tiles (128x128) x 32 L-splits (256 j each).
// block 128: scalar reductions of sp -> scal[0] = sum_c sq[c]*sk[c],
//   scal[1+d] = colsum[d].
// ---------------------------------------------------------------------------
__global__ __launch_bounds__(256) void gram_kernel(
    const short* __restrict__ VTb, const short* __restrict__ KTb,
    const float* __restrict__ sp, float* __restrict__ MT,
    float* __restrict__ scal)
{
  __shared__ __align__(16) short at[128 * 128];   // 32KB VT tile [d][j]
  __shared__ __align__(16) short bt[128 * 128];   // 32KB KT tile [c][j]

  const int tid = threadIdx.x;

  if (blockIdx.x == 128) {
    // scalar block: reduce partials (coalesced row-wise reads of sp)
    float s0 = 0.f, s1 = 0.f, s2 = 0.f;
    for (int rb = 0; rb < 64; ++rb) {
      s0 += sp[(size_t)(0 * 64 + rb) * 256 + tid];
      s1 += sp[(size_t)(1 * 64 + rb) * 256 + tid];
      s2 += sp[(size_t)(2 * 64 + rb) * 256 + tid];
    }
    scal[1 + tid] = s2;                // colsum
    float* red = (float*)at;
    red[tid] = s0 * s1;                // sq[c]*sk[c]
    __syncthreads();
#pragma unroll
    for (int st = 128; st > 0; st >>= 1) {
      if (tid < st) red[tid] += red[tid + st];
      __syncthreads();
    }
    if (tid == 0) scal[0] = red[0];
    return;
  }

  const int tile = blockIdx.x & 3, split = blockIdx.x >> 2;   // split 0..31
  const int d0 = (tile >> 1) * 128, c0 = (tile & 1) * 128;
  const int wid = tid >> 6, lane = tid & 63;
  const int l31 = lane & 31, hi = lane >> 5;
  const int wr = wid >> 1, wc = wid & 1;

  f32x16 acc[2][2] = {};

#pragma unroll
  for (int jj = 0; jj < 2; ++jj) {
    const int j0 = split * 256 + jj * 128;
    __syncthreads();                   // prior-stage readers done
#pragma unroll
    for (int i = 0; i < 8; ++i) {
      int g = i * 256 + tid, rr = g >> 4, p = g & 15;
      gload16(VTb + (size_t)(d0 + rr) * LSEQ + j0 + ((p ^ (rr & 15)) * 8),
              &at[(i * 256 + wid * 64) * 8]);
    }
#pragma unroll
    for (int i = 0; i < 8; ++i) {
      int g = i * 256 + tid, rr = g >> 4, p = g & 15;
      gload16(KTb + (size_t)(c0 + rr) * LSEQ + j0 + ((p ^ (rr & 15)) * 8),
              &bt[(i * 256 + wid * 64) * 8]);
    }
    __syncthreads();                   // drains vmcnt + barrier

#pragma unroll
    for (int kd = 0; kd < 8; ++kd) {
      int ra0 = wr * 64 + l31, ra1 = ra0 + 32;
      int rb0 = wc * 64 + l31, rb1 = rb0 + 32;
      int ck = kd * 2 + hi;
      short8 a0 = *(const short8*)(&at[ra0 * 128 + ((ck ^ (ra0 & 15)) * 8)]);
      short8 a1 = *(const short8*)(&at[ra1 * 128 + ((ck ^ (ra1 & 15)) * 8)]);
      short8 b0 = *(const short8*)(&bt[rb0 * 128 + ((ck ^ (rb0 & 15)) * 8)]);
      short8 b1 = *(const short8*)(&bt[rb1 * 128 + ((ck ^ (rb1 & 15)) * 8)]);
      acc[0][0] = mfma32(a0, b0, acc[0][0]);
      acc[0][1] = mfma32(a0, b1, acc[0][1]);
      acc[1][0] = mfma32(a1, b0, acc[1][0]);
      acc[1][1] = mfma32(a1, b1, acc[1][1]);
    }
  }

  // D: row = d (A), col = c (B); accumulate across splits via fp32 atomics
#pragma unroll
  for (int mt = 0; mt < 2; ++mt)
#pragma unroll
    for (int nt = 0; nt < 2; ++nt) {
      int ccol = c0 + wc * 64 + nt * 32 + l31;
#pragma unroll
      for (int r = 0; r < 16; ++r) {
        int r2 = r ^ (split & 15);     // split-dependent issue order
        int drow = d0 + wr * 64 + mt * 32 + (r2 & 3) + 8 * (r2 >> 2) + 4 * hi;
        atomicAdd(&MT[drow * CH + ccol], acc[mt][nt][r2]);
      }
    }
}

// ---------------------------------------------------------------------------
// Kernel 3: out[i][d] = (colsum[d] + (Q MT^T)[i][d]/L) / (L^2 + zs/L)
// zs/colsum precomputed in gram's scalar block (scal[0], scal[1+d]).
// Same tiling as qkv: "W" = MT fp32 [d][c] -> bf16 LDS; A = Q bf16 rows.
// (R11-verified, unchanged)
// ---------------------------------------------------------------------------
__global__ __launch_bounds__(256) void final_kernel(
    const short* __restrict__ Qb, const float* __restrict__ MT,
    const float* __restrict__ scal, float* __restrict__ out)
{
  __shared__ __align__(16) short wt[128 * 256];   // 64KB

  const int tid = threadIdx.x;
  const float Zinv = 1.0f / (67108864.0f + scal[0] * (1.0f / 8192.0f));

  const int rb = blockIdx.x >> 1, cb = blockIdx.x & 1;
  const int row0 = rb * 128, col0 = cb * 128;

#pragma unroll
  for (int i = 0; i < 16; ++i) {
    int g = i * 256 + tid;
    int rr = g >> 5, p = g & 31;
    const float4* src = (const float4*)(MT + (col0 + rr) * CH + ((p ^ (rr & 31)) * 8));
    *(short8*)(&wt[rr * 256 + p * 8]) = cvt8(src[0], src[1]);
  }
  __syncthreads();

  const int wid = tid >> 6, lane = tid & 63, l31 = lane & 31, hi = lane >> 5;
  const int wrow0 = row0 + wid * 32;

  short8 qf[16];
#pragma unroll
  for (int kd = 0; kd < 16; ++kd)
    qf[kd] = *(const short8*)(Qb + (size_t)(wrow0 + l31) * CH + kd * 16 + hi * 8);

  f32x16 acc[4] = {};
#pragma unroll
  for (int kd = 0; kd < 16; ++kd)
#pragma unroll
    for (int nf = 0; nf < 4; ++nf) {
      int r = nf * 32 + l31;
      short8 bf = *(const short8*)(&wt[r * 256 + (((kd * 2 + hi) ^ (r & 31)) * 8)]);
      acc[nf] = mfma32(qf[kd], bf, acc[nf]);
    }

#pragma unroll
  for (int nf = 0; nf < 4; ++nf) {
    int col = col0 + nf * 32 + l31;
    float cs = scal[1 + col];
#pragma unroll
    for (int r = 0; r < 16; ++r) {
      int row = wrow0 + (r & 3) + 8 * (r >> 2) + 4 * hi;
      out[(size_t)row * CH + col] = (cs + acc[nf][r] * (1.0f / 8192.0f)) * Zinv;
    }
  }
}

// ---------------------------------------------------------------------------
extern "C" void kernel_launch(void* const* d_in, const int* in_sizes, int n_in,
                              void* d_out, int out_size, void* d_ws, size_t ws_size,
                              hipStream_t stream) {
  const float* x  = (const float*)d_in[0];
  const float* Wq = (const float*)d_in[1];
  const float* bq = (const float*)d_in[2];
  const float* Wk = (const float*)d_in[3];
  const float* bk = (const float*)d_in[4];
  const float* Wv = (const float*)d_in[5];
  const float* bv = (const float*)d_in[6];
  float* out = (float*)d_out;

  // workspace: Q(4MB) | KT(4MB) | VT(4MB) | MT(256KB) | sp(192KB) | scal(1KB+)
  char* ws = (char*)d_ws;
  short* Qb  = (short*)ws;
  short* KTb = Qb  + (size_t)LSEQ * CH;
  short* VTb = KTb + (size_t)CH * LSEQ;
  float* MT   = (float*)(VTb + (size_t)CH * LSEQ);
  float* sp   = MT + (size_t)CH * CH;          // [3][64][256] partial col-sums
  float* scal = sp + (size_t)3 * 64 * 256;     // [0]=zs, [1..256]=colsum

  qkv_kernel<<<dim3(64, 3), 256, 0, stream>>>(x, Wq, bq, Wk, bk, Wv, bv,
                                              Qb, KTb, VTb, sp, MT);
  gram_kernel<<<129, 256, 0, stream>>>(VTb, KTb, sp, MT, scal);
  final_kernel<<<128, 256, 0, stream>>>(Qb, MT, scal, out);
}

// Round 15
// 38.395 us; speedup vs baseline: 3.5021x; 1.3118x over previous
//
#include <hip/hip_runtime.h>

#define LSEQ 8192
#define CH   256

typedef __attribute__((ext_vector_type(8)))  short short8;
typedef __attribute__((ext_vector_type(4)))  short short4v;
typedef __attribute__((ext_vector_type(16))) float f32x16;
typedef unsigned int u32;

// bf16 converts via v_cvt_pk_bf16_f32 (RNE)
__device__ __forceinline__ short f2bf(float f) {
  u32 r;
  asm("v_cvt_pk_bf16_f32 %0, %1, %1" : "=v"(r) : "v"(f));
  return (short)r;
}
__device__ __forceinline__ u32 pk2bf(float a, float b) {
  u32 r;
  asm("v_cvt_pk_bf16_f32 %0, %1, %2" : "=v"(r) : "v"(a), "v"(b));
  return r;
}
__device__ __forceinline__ short8 cvt8(float4 a, float4 b) {
  union { u32 u[4]; short8 s; } v;
  v.u[0] = pk2bf(a.x, a.y); v.u[1] = pk2bf(a.z, a.w);
  v.u[2] = pk2bf(b.x, b.y); v.u[3] = pk2bf(b.z, b.w);
  return v.s;
}
__device__ __forceinline__ short4v pk4bf(float a, float b, float c, float d) {
  union { u32 u[2]; short4v s; } v;
  v.u[0] = pk2bf(a, b); v.u[1] = pk2bf(c, d);
  return v.s;
}
__device__ inline f32x16 mfma32(short8 a, short8 b, f32x16 c) {
  return __builtin_amdgcn_mfma_f32_32x32x16_bf16(a, b, c, 0, 0, 0);
}
// async global -> LDS, 16B per lane; dest = wave-uniform base (+ lane*16 by HW)
__device__ __forceinline__ void gload16(const void* g, void* l) {
  __builtin_amdgcn_global_load_lds(
      (const __attribute__((address_space(1))) u32*)g,
      (__attribute__((address_space(3))) u32*)l, 16, 0, 0);
}

// ---------------------------------------------------------------------------
// Kernel 1: QKV projection, 128x128 tiles, 32x32x16 bf16 MFMA.  [R11-verified]
//   m=0 -> Qb [row][c] bf16 row-major   (+ these blocks zero MT: plain stores)
//   m=1 -> KTb[c][row] bf16 transposed
//   m=2 -> VTb[d][row] bf16 transposed
// Column-sums: plain-stored partials sp[m][rb][col] (no atomics, no memset).
// W tile [128 outcols][256] fp32 -> bf16 LDS, 16B-chunk XOR swizzle ^(row&31).
// ---------------------------------------------------------------------------
__global__ __launch_bounds__(256) void qkv_kernel(
    const float* __restrict__ x,
    const float* __restrict__ Wq, const float* __restrict__ bq,
    const float* __restrict__ Wk, const float* __restrict__ bk,
    const float* __restrict__ Wv, const float* __restrict__ bv,
    short* __restrict__ Qb, short* __restrict__ KTb, short* __restrict__ VTb,
    float* __restrict__ sp, float* __restrict__ MT)
{
  const int m = blockIdx.y;
  const float* W  = (m == 0) ? Wq : ((m == 1) ? Wk : Wv);
  const float* bp = (m == 0) ? bq : ((m == 1) ? bk : bv);
  const int rb = blockIdx.x >> 1, cb = blockIdx.x & 1;
  const int row0 = rb * 128, col0 = cb * 128;

  __shared__ __align__(16) short wt[128 * 256];   // 64KB
  __shared__ float colred[4][128];

  const int tid = threadIdx.x;

  // m=0 blocks also zero MT (disjoint 512-float slices; read only by gram)
  if (m == 0 && tid < 128) {
    float4 z = {0.f, 0.f, 0.f, 0.f};
    ((float4*)(MT + (size_t)blockIdx.x * 512))[tid] = z;
  }

#pragma unroll
  for (int i = 0; i < 16; ++i) {
    int g = i * 256 + tid;             // 16B bf16 chunk (8 elems / 32B fp32)
    int rr = g >> 5, p = g & 31;
    const float4* src = (const float4*)(W + (col0 + rr) * CH + ((p ^ (rr & 31)) * 8));
    *(short8*)(&wt[rr * 256 + p * 8]) = cvt8(src[0], src[1]);
  }
  __syncthreads();

  const int wid = tid >> 6, lane = tid & 63, l31 = lane & 31, hi = lane >> 5;
  const int wrow0 = row0 + wid * 32;

  f32x16 acc[4] = {};
#pragma unroll
  for (int kd = 0; kd < 16; ++kd) {
    const float4* xs = (const float4*)(x + (size_t)(wrow0 + l31) * CH + kd * 16 + hi * 8);
    short8 af = cvt8(xs[0], xs[1]);
#pragma unroll
    for (int nf = 0; nf < 4; ++nf) {
      int r = nf * 32 + l31;
      short8 bf = *(const short8*)(&wt[r * 256 + (((kd * 2 + hi) ^ (r & 31)) * 8)]);
      acc[nf] = mfma32(af, bf, acc[nf]);   // D: row=x-row, col=W-row(outcol)
    }
  }

  // D layout: col = l31 (+32*nf), row = wrow0 + (r&3) + 8*(r>>2) + 4*hi
#pragma unroll
  for (int nf = 0; nf < 4; ++nf) {
    int col = col0 + nf * 32 + l31;
    float bias = bp[col];
    float cs = 0.f;
    if (m == 0) {
#pragma unroll
      for (int r = 0; r < 16; ++r) {
        float y = acc[nf][r] + bias;
        cs += y;
        int row = wrow0 + (r & 3) + 8 * (r >> 2) + 4 * hi;
        Qb[(size_t)row * CH + col] = f2bf(y);
      }
    } else {
      short* dst = (m == 1) ? KTb : VTb;
#pragma unroll
      for (int g = 0; g < 4; ++g) {
        float y0 = acc[nf][g * 4 + 0] + bias;
        float y1 = acc[nf][g * 4 + 1] + bias;
        float y2 = acc[nf][g * 4 + 2] + bias;
        float y3 = acc[nf][g * 4 + 3] + bias;
        cs += (y0 + y1) + (y2 + y3);
        *(short4v*)(&dst[(size_t)col * LSEQ + wrow0 + g * 8 + hi * 4]) =
            pk4bf(y0, y1, y2, y3);
      }
    }
    cs += __shfl_xor(cs, 32);          // add other hi-half: 32-row sum
    if (hi == 0) colred[wid][nf * 32 + l31] = cs;
  }
  __syncthreads();
  if (tid < 128) {
    float s = colred[0][tid] + colred[1][tid] + colred[2][tid] + colred[3][tid];
    sp[((size_t)m * 64 + rb) * 256 + col0 + tid] = s;   // plain partial store
  }
}

// ---------------------------------------------------------------------------
// Kernel 2: blocks 0..63: MT[d][c] += V^T K partials (fp32 atomics),
//   4 output tiles (128x128) x 16 L-splits (512 j each).
// block 64: scalar reductions of sp -> scal[0] = sum_c sq[c]*sk[c],
//   scal[1+d] = colsum[d].                              [R11-verified]
// ---------------------------------------------------------------------------
__global__ __launch_bounds__(256) void gram_kernel(
    const short* __restrict__ VTb, const short* __restrict__ KTb,
    const float* __restrict__ sp, float* __restrict__ MT,
    float* __restrict__ scal)
{
  __shared__ __align__(16) short at[128 * 128];   // 32KB VT tile [d][j]
  __shared__ __align__(16) short bt[128 * 128];   // 32KB KT tile [c][j]

  const int tid = threadIdx.x;

  if (blockIdx.x == 64) {
    // scalar block: reduce partials (coalesced row-wise reads of sp)
    float s0 = 0.f, s1 = 0.f, s2 = 0.f;
    for (int rb = 0; rb < 64; ++rb) {
      s0 += sp[(size_t)(0 * 64 + rb) * 256 + tid];
      s1 += sp[(size_t)(1 * 64 + rb) * 256 + tid];
      s2 += sp[(size_t)(2 * 64 + rb) * 256 + tid];
    }
    scal[1 + tid] = s2;                // colsum
    float* red = (float*)at;
    red[tid] = s0 * s1;                // sq[c]*sk[c]
    __syncthreads();
#pragma unroll
    for (int st = 128; st > 0; st >>= 1) {
      if (tid < st) red[tid] += red[tid + st];
      __syncthreads();
    }
    if (tid == 0) scal[0] = red[0];
    return;
  }

  const int tile = blockIdx.x & 3, split = blockIdx.x >> 2;   // split 0..15
  const int d0 = (tile >> 1) * 128, c0 = (tile & 1) * 128;
  const int wid = tid >> 6, lane = tid & 63;
  const int l31 = lane & 31, hi = lane >> 5;
  const int wr = wid >> 1, wc = wid & 1;

  f32x16 acc[2][2] = {};

#pragma unroll
  for (int jj = 0; jj < 4; ++jj) {
    const int j0 = split * 512 + jj * 128;
    __syncthreads();                   // prior-stage readers done
#pragma unroll
    for (int i = 0; i < 8; ++i) {
      int g = i * 256 + tid, rr = g >> 4, p = g & 15;
      gload16(VTb + (size_t)(d0 + rr) * LSEQ + j0 + ((p ^ (rr & 15)) * 8),
              &at[(i * 256 + wid * 64) * 8]);
    }
#pragma unroll
    for (int i = 0; i < 8; ++i) {
      int g = i * 256 + tid, rr = g >> 4, p = g & 15;
      gload16(KTb + (size_t)(c0 + rr) * LSEQ + j0 + ((p ^ (rr & 15)) * 8),
              &bt[(i * 256 + wid * 64) * 8]);
    }
    __syncthreads();                   // drains vmcnt + barrier

#pragma unroll
    for (int kd = 0; kd < 8; ++kd) {
      int ra0 = wr * 64 + l31, ra1 = ra0 + 32;
      int rb0 = wc * 64 + l31, rb1 = rb0 + 32;
      int ck = kd * 2 + hi;
      short8 a0 = *(const short8*)(&at[ra0 * 128 + ((ck ^ (ra0 & 15)) * 8)]);
      short8 a1 = *(const short8*)(&at[ra1 * 128 + ((ck ^ (ra1 & 15)) * 8)]);
      short8 b0 = *(const short8*)(&bt[rb0 * 128 + ((ck ^ (rb0 & 15)) * 8)]);
      short8 b1 = *(const short8*)(&bt[rb1 * 128 + ((ck ^ (rb1 & 15)) * 8)]);
      acc[0][0] = mfma32(a0, b0, acc[0][0]);
      acc[0][1] = mfma32(a0, b1, acc[0][1]);
      acc[1][0] = mfma32(a1, b0, acc[1][0]);
      acc[1][1] = mfma32(a1, b1, acc[1][1]);
    }
  }

  // D: row = d (A), col = c (B); accumulate across splits via fp32 atomics
#pragma unroll
  for (int mt = 0; mt < 2; ++mt)
#pragma unroll
    for (int nt = 0; nt < 2; ++nt) {
      int ccol = c0 + wc * 64 + nt * 32 + l31;
#pragma unroll
      for (int r = 0; r < 16; ++r) {
        int r2 = r ^ (split & 15);     // split-dependent issue order
        int drow = d0 + wr * 64 + mt * 32 + (r2 & 3) + 8 * (r2 >> 2) + 4 * hi;
        atomicAdd(&MT[drow * CH + ccol], acc[mt][nt][r2]);
      }
    }
}

// ---------------------------------------------------------------------------
// Kernel 3: out[i][d] = (colsum[d] + (Q MT^T)[i][d]/L) / (L^2 + zs/L)
// zs/colsum precomputed in gram's scalar block (scal[0], scal[1+d]).
// Same tiling as qkv: "W" = MT fp32 [d][c] -> bf16 LDS; A = Q bf16 rows.
// [R11-verified]
// ---------------------------------------------------------------------------
__global__ __launch_bounds__(256) void final_kernel(
    const short* __restrict__ Qb, const float* __restrict__ MT,
    const float* __restrict__ scal, float* __restrict__ out)
{
  __shared__ __align__(16) short wt[128 * 256];   // 64KB

  const int tid = threadIdx.x;
  const float Zinv = 1.0f / (67108864.0f + scal[0] * (1.0f / 8192.0f));

  const int rb = blockIdx.x >> 1, cb = blockIdx.x & 1;
  const int row0 = rb * 128, col0 = cb * 128;

#pragma unroll
  for (int i = 0; i < 16; ++i) {
    int g = i * 256 + tid;
    int rr = g >> 5, p = g & 31;
    const float4* src = (const float4*)(MT + (col0 + rr) * CH + ((p ^ (rr & 31)) * 8));
    *(short8*)(&wt[rr * 256 + p * 8]) = cvt8(src[0], src[1]);
  }
  __syncthreads();

  const int wid = tid >> 6, lane = tid & 63, l31 = lane & 31, hi = lane >> 5;
  const int wrow0 = row0 + wid * 32;

  short8 qf[16];
#pragma unroll
  for (int kd = 0; kd < 16; ++kd)
    qf[kd] = *(const short8*)(Qb + (size_t)(wrow0 + l31) * CH + kd * 16 + hi * 8);

  f32x16 acc[4] = {};
#pragma unroll
  for (int kd = 0; kd < 16; ++kd)
#pragma unroll
    for (int nf = 0; nf < 4; ++nf) {
      int r = nf * 32 + l31;
      short8 bf = *(const short8*)(&wt[r * 256 + (((kd * 2 + hi) ^ (r & 31)) * 8)]);
      acc[nf] = mfma32(qf[kd], bf, acc[nf]);
    }

#pragma unroll
  for (int nf = 0; nf < 4; ++nf) {
    int col = col0 + nf * 32 + l31;
    float cs = scal[1 + col];
#pragma unroll
    for (int r = 0; r < 16; ++r) {
      int row = wrow0 + (r & 3) + 8 * (r >> 2) + 4 * hi;
      out[(size_t)row * CH + col] = (cs + acc[nf][r] * (1.0f / 8192.0f)) * Zinv;
    }
  }
}

// ---------------------------------------------------------------------------
extern "C" void kernel_launch(void* const* d_in, const int* in_sizes, int n_in,
                              void* d_out, int out_size, void* d_ws, size_t ws_size,
                              hipStream_t stream) {
  const float* x  = (const float*)d_in[0];
  const float* Wq = (const float*)d_in[1];
  const float* bq = (const float*)d_in[2];
  const float* Wk = (const float*)d_in[3];
  const float* bk = (const float*)d_in[4];
  const float* Wv = (const float*)d_in[5];
  const float* bv = (const float*)d_in[6];
  float* out = (float*)d_out;

  // workspace: Q(4MB) | KT(4MB) | VT(4MB) | MT(256KB) | sp(192KB) | scal(1KB+)
  char* ws = (char*)d_ws;
  short* Qb  = (short*)ws;
  short* KTb = Qb  + (size_t)LSEQ * CH;
  short* VTb = KTb + (size_t)CH * LSEQ;
  float* MT   = (float*)(VTb + (size_t)CH * LSEQ);
  float* sp   = MT + (size_t)CH * CH;          // [3][64][256] partial col-sums
  float* scal = sp + (size_t)3 * 64 * 256;     // [0]=zs, [1..256]=colsum

  qkv_kernel<<<dim3(128, 3), 256, 0, stream>>>(x, Wq, bq, Wk, bk, Wv, bv,
                                               Qb, KTb, VTb, sp, MT);
  gram_kernel<<<65, 256, 0, stream>>>(VTb, KTb, sp, MT, scal);
  final_kernel<<<128, 256, 0, stream>>>(Qb, MT, scal, out);
}